// Round 13
// baseline (277.929 us; speedup 1.0000x reference)
//
#include <hip/hip_runtime.h>
#include <hip/hip_bf16.h>
#include <math.h>

// Problem constants (fixed by reference setup_inputs)
#define BB 16
#define NN 64
#define ATTR 4
#define STATE 16
#define RELD 9
#define GG 32
#define NF 256
#define NROWS_OBJ (BB*NN)        // 1024
#define NROWS_REL (BB*NN*NN)     // 65536

typedef _Float16 half8 __attribute__((ext_vector_type(8)));
typedef float  floatx4 __attribute__((ext_vector_type(4)));
typedef unsigned short ushort_t;

// fp16 split: x ~= h + l, |x-(h+l)| ~ 2^-22 |x| (A-operand use only)
__device__ __forceinline__ void split2h(float x, _Float16& h, _Float16& l) {
  h = (_Float16)x;
  l = (_Float16)(x - (float)h);
}

#define F0_ELEMS (2 * 16 * 64 * 8)   // 16384
#define F1_ELEMS (8 * 16 * 64 * 8)   // 65536
#define F_TOTAL  (F0_ELEMS + 2 * F1_ELEMS)

// ---------------------------------------------------------------------------
// Fused encoder + Q/R + weight-fragment prep (R10 version — R11's LDS
// staging was neutral, reverted for simplicity).
// ---------------------------------------------------------------------------
__global__ __launch_bounds__(1024) void enc_qr_prep_kernel(
    const float* __restrict__ attrs, const float* __restrict__ states,
    const float* __restrict__ w0, const float* __restrict__ b0,
    const float* __restrict__ w1, const float* __restrict__ b1,
    const float* __restrict__ rpw, const float* __restrict__ rpb,
    const float* __restrict__ rel_w0, const float* __restrict__ rel_w1,
    _Float16* __restrict__ F0, _Float16* __restrict__ F1,
    _Float16* __restrict__ F2,
    float* __restrict__ obj, float* __restrict__ Q, float* __restrict__ R)
{
  int tid = threadIdx.x;
  for (int idx = blockIdx.x * 1024 + tid; idx < F_TOTAL; idx += 256 * 1024) {
    if (idx < F0_ELEMS) {
      int j = idx & 7, lane = (idx >> 3) & 63, g = (idx >> 9) & 15, s = idx >> 13;
      int k = s * 32 + (lane >> 4) * 8 + j, n = g * 16 + (lane & 15);
      float v = (k < 33) ? rel_w0[k * NF + n] : 0.f;
      F0[idx] = (_Float16)v;
    } else if (idx < F0_ELEMS + F1_ELEMS) {
      int t = idx - F0_ELEMS;
      int j = t & 7, lane = (t >> 3) & 63, g = (t >> 9) & 15, s = t >> 13;
      int k = s * 32 + (lane >> 4) * 8 + j, n = g * 16 + (lane & 15);
      F1[t] = (_Float16)rel_w1[k * NF + n];
    } else {
      int t = idx - (F0_ELEMS + F1_ELEMS);
      int j = t & 7, lane = (t >> 3) & 63, g = (t >> 9) & 15, s = t >> 13;
      int k = s * 32 + (lane >> 4) * 8 + j, n = g * 16 + (lane & 15);
      F2[t] = (_Float16)rpw[k * NF + n];
    }
  }
  __shared__ float X[4 * 20];
  __shared__ float H[4 * NF];
  __shared__ float O[4 * NF];
  int row0 = blockIdx.x * 4;
  if (tid < 80) {
    int r = tid / 20, k = tid % 20;
    int m = row0 + r;
    X[tid] = (k < ATTR) ? attrs[m * ATTR + k] : states[m * STATE + (k - ATTR)];
  }
  __syncthreads();
  int r = tid >> 8, c = tid & 255;
  float a = b0[c];
#pragma unroll
  for (int k = 0; k < 20; ++k) a += X[r * 20 + k] * w0[k * NF + c];
  H[r * NF + c] = fmaxf(a, 0.f);
  __syncthreads();
  a = b1[c];
#pragma unroll 8
  for (int k = 0; k < NF; ++k) a += H[r * NF + k] * w1[k * NF + c];
  a = fmaxf(a, 0.f);
  O[r * NF + c] = a;
  obj[(row0 + r) * NF + c] = a;
  __syncthreads();
  a = rpb[c];
#pragma unroll 8
  for (int k = 0; k < NF; ++k) a += O[r * NF + k] * rpw[(256 + k) * NF + c];
  Q[(row0 + r) * NF + c] = a;
  a = 0.f;
#pragma unroll 8
  for (int k = 0; k < NF; ++k) a += O[r * NF + k] * rpw[(512 + k) * NF + c];
  R[(row0 + r) * NF + c] = a;
}

// ---------------------------------------------------------------------------
// Relation chain, fp16 A-split x B-single MFMA (FROZEN from R10: ~59us,
// absmax 0.0156): run ONCE, stage-3 P-tile in regs -> fp32 P store + fused
// pstep-1 aggregation epilogue.
// ---------------------------------------------------------------------------
#define ROWS 32
#define NRT 2
#define HSTR 264
#define XSTR 72

__global__ __launch_bounds__(256, 4) void rel_agg_store_mfma(
    const float* __restrict__ attrs, const float* __restrict__ states,
    const float* __restrict__ rel_attrs,
    const _Float16* __restrict__ F0, const float* __restrict__ b0,
    const _Float16* __restrict__ F1, const float* __restrict__ b1,
    const _Float16* __restrict__ F2,
    const float* __restrict__ Q, const float* __restrict__ R,
    float* __restrict__ P, float* __restrict__ part)
{
  __shared__ __align__(16) _Float16 S[2 * ROWS * HSTR];   // 33792 B
  _Float16* Hh = S;
  _Float16* Hl = S + ROWS * HSTR;
  _Float16* Xh = Hh;   // X aliased onto H (dead after stage 1)
  _Float16* Xl = Hl;

  int tid  = threadIdx.x;
  int wave = tid >> 6;
  int lane = tid & 63;
  int quad = lane >> 4;
  int l16  = lane & 15;
  int row0 = blockIdx.x * ROWS;

  for (int idx = tid; idx < ROWS * 64; idx += 256) {
    int r = idx >> 6, k = idx & 63;
    int grow = row0 + r;
    int j = grow & 63, i = (grow >> 6) & 63, b = grow >> 12;
    float v = 0.f;
    if (k < RELD)                     v = rel_attrs[(size_t)grow * RELD + k];
    else if (k < RELD + STATE)        v = states[(b * NN + i) * STATE + (k - RELD)]
                                        - states[(b * NN + j) * STATE + (k - RELD)];
    else if (k < RELD + STATE + ATTR) v = attrs[(b * NN + i) * ATTR + (k - RELD - STATE)];
    else if (k < 33)                  v = attrs[(b * NN + j) * ATTR + (k - RELD - STATE - ATTR)];
    _Float16 h, l; split2h(v, h, l);
    Xh[r * XSTR + k] = h;
    Xl[r * XSTR + k] = l;
  }
  __syncthreads();

  floatx4 acc[NRT][4];

#define ZERO_ACC() do { \
  _Pragma("unroll") for (int rt = 0; rt < NRT; ++rt) \
  _Pragma("unroll") for (int ct = 0; ct < 4; ++ct) acc[rt][ct] = (floatx4)(0.f); } while (0)

#define STAGE(Sn, AH, AL, ASTR, BF) do { \
  half8 ah[2][NRT], al[2][NRT], bf[2][4]; \
  _Pragma("unroll") for (int ct = 0; ct < 4; ++ct) \
    bf[0][ct] = *(const half8*)((BF) + (size_t)((wave * 4 + ct) * 64 + lane) * 8); \
  _Pragma("unroll") for (int rt = 0; rt < NRT; ++rt) { \
    ah[0][rt] = *(const half8*)(&(AH)[(rt * 16 + l16) * (ASTR) + quad * 8]); \
    al[0][rt] = *(const half8*)(&(AL)[(rt * 16 + l16) * (ASTR) + quad * 8]); } \
  _Pragma("unroll") \
  for (int s = 0; s < (Sn); ++s) { \
    int cur = s & 1, nxt = cur ^ 1; \
    if (s + 1 < (Sn)) { \
      _Pragma("unroll") for (int ct = 0; ct < 4; ++ct) \
        bf[nxt][ct] = *(const half8*)((BF) + (size_t)(((s + 1) * 16 + wave * 4 + ct) * 64 + lane) * 8); \
      _Pragma("unroll") for (int rt = 0; rt < NRT; ++rt) { \
        ah[nxt][rt] = *(const half8*)(&(AH)[(rt * 16 + l16) * (ASTR) + (s + 1) * 32 + quad * 8]); \
        al[nxt][rt] = *(const half8*)(&(AL)[(rt * 16 + l16) * (ASTR) + (s + 1) * 32 + quad * 8]); } } \
    _Pragma("unroll") for (int rt = 0; rt < NRT; ++rt) \
    _Pragma("unroll") for (int ct = 0; ct < 4; ++ct) { \
      acc[rt][ct] = __builtin_amdgcn_mfma_f32_16x16x32_f16(ah[cur][rt], bf[cur][ct], acc[rt][ct], 0, 0, 0); \
      acc[rt][ct] = __builtin_amdgcn_mfma_f32_16x16x32_f16(al[cur][rt], bf[cur][ct], acc[rt][ct], 0, 0, 0); } \
  } } while (0)

  // ---- stage 1: H = ReLU(X @ W0 + b0), K=64 (padded)
  ZERO_ACC();
  STAGE(2, Xh, Xl, XSTR, F0);
  __syncthreads();  // X reads done before H overwrites the aliased region
#pragma unroll
  for (int ct = 0; ct < 4; ++ct) {
    int col = wave * 64 + ct * 16 + l16;
    float bias = b0[col];
#pragma unroll
    for (int rt = 0; rt < NRT; ++rt)
#pragma unroll
      for (int r = 0; r < 4; ++r) {
        int row = rt * 16 + quad * 4 + r;
        float h = fmaxf(acc[rt][ct][r] + bias, 0.f);
        split2h(h, Hh[row * HSTR + col], Hl[row * HSTR + col]);
      }
  }
  __syncthreads();

  // ---- stage 2: E = ReLU(H @ W1 + b1), K=256
  ZERO_ACC();
  STAGE(8, Hh, Hl, HSTR, F1);
  __syncthreads();
#pragma unroll
  for (int ct = 0; ct < 4; ++ct) {
    int col = wave * 64 + ct * 16 + l16;
    float bias = b1[col];
#pragma unroll
    for (int rt = 0; rt < NRT; ++rt)
#pragma unroll
      for (int r = 0; r < 4; ++r) {
        int row = rt * 16 + quad * 4 + r;
        float e = fmaxf(acc[rt][ct][r] + bias, 0.f);
        split2h(e, Hh[row * HSTR + col], Hl[row * HSTR + col]);
      }
  }
  __syncthreads();

  // ---- stage 3: P-tile in registers (K=256)
  ZERO_ACC();
  STAGE(8, Hh, Hl, HSTR, F2);

  // ---- store P fp32 (pstep 2 reads it via agg_part)
#pragma unroll
  for (int ct = 0; ct < 4; ++ct) {
    int col = wave * 64 + ct * 16 + l16;
#pragma unroll
    for (int rt = 0; rt < NRT; ++rt)
#pragma unroll
      for (int r = 0; r < 4; ++r) {
        int row = rt * 16 + quad * 4 + r;
        P[(size_t)(row0 + row) * NF + col] = acc[rt][ct][r];
      }
  }
  __syncthreads();                       // all E reads done — LDS reusable

  // ---- fused pstep-1 aggregation epilogue
  {
    float* Rs = (float*)S;               // 32 x 256 fp32 R-tile (32KB)
    int bi    = row0 >> 6;
    int jbase = row0 & 63;               // 0 or 32
    int b     = row0 >> 12;
    for (int idx = tid; idx < ROWS * NF; idx += 256) {
      int rr = idx >> 8, cc = idx & 255;
      Rs[idx] = R[(size_t)(b * NN + jbase + rr) * NF + cc];
    }
    __syncthreads();
#pragma unroll
    for (int ct = 0; ct < 4; ++ct) {
      int col = wave * 64 + ct * 16 + l16;
      float q = Q[bi * NF + col];
      float s = 0.f;
#pragma unroll
      for (int rt = 0; rt < NRT; ++rt)
#pragma unroll
        for (int r = 0; r < 4; ++r) {
          int row = rt * 16 + quad * 4 + r;
          s += fmaxf(acc[rt][ct][r] + q + Rs[row * NF + col], 0.f);
        }
      s += __shfl_xor(s, 16, 64);        // quad butterfly: rows 0..31 summed
      s += __shfl_xor(s, 32, 64);
      if (quad == 0)
        part[((size_t)bi * 2 + (jbase >> 5)) * NF + col] = s;
    }
  }
#undef ZERO_ACC
#undef STAGE
}

// ---------------------------------------------------------------------------
// upd_qr: G = part1 halves summed; obj' = ReLU([obj,G]@pp_w+pp_b); Q',R'.
// (R10 version)
// ---------------------------------------------------------------------------
__global__ __launch_bounds__(1024) void upd_qr_kernel(
    const float* __restrict__ part, const float* __restrict__ obj,
    const float* __restrict__ ppw, const float* __restrict__ ppb,
    const float* __restrict__ rpw, const float* __restrict__ rpb,
    float* __restrict__ obj_out, float* __restrict__ Qo, float* __restrict__ Ro)
{
  __shared__ float A[4 * NF];
  __shared__ float G[4 * NF];
  int tid = threadIdx.x;
  int row0 = blockIdx.x * 4;
  int r = tid >> 8, c = tid & 255;
  A[r * NF + c] = obj[(row0 + r) * NF + c];
  G[r * NF + c] = part[((size_t)(row0 + r) * 2 + 0) * NF + c]
                + part[((size_t)(row0 + r) * 2 + 1) * NF + c];
  __syncthreads();
  float a = ppb[c];
#pragma unroll 8
  for (int k = 0; k < NF; ++k) a += A[r * NF + k] * ppw[k * NF + c];
#pragma unroll 8
  for (int k = 0; k < NF; ++k) a += G[r * NF + k] * ppw[(NF + k) * NF + c];
  float o = fmaxf(a, 0.f);
  __syncthreads();                 // all reads of old A done
  A[r * NF + c] = o;
  obj_out[(row0 + r) * NF + c] = o;
  __syncthreads();
  a = rpb[c];
#pragma unroll 8
  for (int k = 0; k < NF; ++k) a += A[r * NF + k] * rpw[(256 + k) * NF + c];
  Qo[(row0 + r) * NF + c] = a;
  a = 0.f;
#pragma unroll 8
  for (int k = 0; k < NF; ++k) a += A[r * NF + k] * rpw[(512 + k) * NF + c];
  Ro[(row0 + r) * NF + c] = a;
}

// ---------------------------------------------------------------------------
// agg_part v2: float4 streaming sweep of P.
// grid (1024, 2) x 256 threads. Thread: c4=(tid&63)*4, jq=tid>>6 (8 j's).
// 16 outstanding float4 loads/thread, fully coalesced (16B/lane sweet spot).
// 4-way LDS reduce -> part[bi][jh][c] (2 slices).
// ---------------------------------------------------------------------------
__global__ __launch_bounds__(256) void agg_part_kernel(
    const float* __restrict__ P, const float* __restrict__ Q,
    const float* __restrict__ R, float* __restrict__ part)
{
  __shared__ float red[4 * NF];
  int bi = blockIdx.x;
  int jh = blockIdx.y;
  int tid = threadIdx.x;
  int c4 = (tid & 63) * 4;
  int jq = tid >> 6;
  int b = bi >> 6;
  float4 q4 = *(const float4*)(Q + bi * NF + c4);
  const float* Pb = P + ((size_t)bi * NN + jh * 32 + jq * 8) * NF + c4;
  const float* Rb = R + (size_t)(b * NN + jh * 32 + jq * 8) * NF + c4;
  float4 s = make_float4(0.f, 0.f, 0.f, 0.f);
#pragma unroll
  for (int j = 0; j < 8; ++j) {
    float4 p  = *(const float4*)(Pb + (size_t)j * NF);
    float4 rv = *(const float4*)(Rb + (size_t)j * NF);
    s.x += fmaxf(p.x + q4.x + rv.x, 0.f);
    s.y += fmaxf(p.y + q4.y + rv.y, 0.f);
    s.z += fmaxf(p.z + q4.z + rv.z, 0.f);
    s.w += fmaxf(p.w + q4.w + rv.w, 0.f);
  }
  *(float4*)(&red[jq * NF + c4]) = s;
  __syncthreads();
  if (jq == 0) {
    float4 t0 = *(const float4*)(&red[0 * NF + c4]);
    float4 t1 = *(const float4*)(&red[1 * NF + c4]);
    float4 t2 = *(const float4*)(&red[2 * NF + c4]);
    float4 t3 = *(const float4*)(&red[3 * NF + c4]);
    float4 o;
    o.x = t0.x + t1.x + t2.x + t3.x;
    o.y = t0.y + t1.y + t2.y + t3.y;
    o.z = t0.z + t1.z + t2.z + t3.z;
    o.w = t0.w + t1.w + t2.w + t3.w;
    *(float4*)(part + ((size_t)bi * 2 + jh) * NF + c4) = o;
  }
}

// ---------------------------------------------------------------------------
// Final update + predictor (part now 2 slices, matching upd_qr).
// ---------------------------------------------------------------------------
__global__ __launch_bounds__(1024) void upd_pred_kernel(
    const float* __restrict__ part, const float* __restrict__ obj,
    const float* __restrict__ ppw, const float* __restrict__ ppb,
    const float* __restrict__ w0, const float* __restrict__ b0,
    const float* __restrict__ w1, const float* __restrict__ b1,
    float* __restrict__ out)
{
  __shared__ float A[4 * NF];
  __shared__ float G[4 * NF];
  int tid = threadIdx.x;
  int row0 = blockIdx.x * 4;
  int r = tid >> 8, c = tid & 255;
  A[r * NF + c] = obj[(row0 + r) * NF + c];
  G[r * NF + c] = part[((size_t)(row0 + r) * 2 + 0) * NF + c]
                + part[((size_t)(row0 + r) * 2 + 1) * NF + c];
  __syncthreads();
  float a = ppb[c];
#pragma unroll 8
  for (int k = 0; k < NF; ++k) a += A[r * NF + k] * ppw[k * NF + c];
#pragma unroll 8
  for (int k = 0; k < NF; ++k) a += G[r * NF + k] * ppw[(NF + k) * NF + c];
  float o = fmaxf(a, 0.f);
  __syncthreads();                 // old A reads done
  A[r * NF + c] = o;
  __syncthreads();
  a = b0[c];
#pragma unroll 8
  for (int k = 0; k < NF; ++k) a += A[r * NF + k] * w0[k * NF + c];
  G[r * NF + c] = fmaxf(a, 0.f);
  __syncthreads();
  if (tid < 4 * GG) {
    int rr = tid >> 5, g = tid & 31;
    a = b1[g];
    const float* Tr = G + rr * NF;
#pragma unroll 8
    for (int k = 0; k < NF; ++k) a += Tr[k] * w1[k * GG + g];
    out[(row0 + rr) * GG + g] = tanhf(a);
  }
}

extern "C" void kernel_launch(void* const* d_in, const int* in_sizes, int n_in,
                              void* d_out, int out_size, void* d_ws, size_t ws_size,
                              hipStream_t stream)
{
  const float* attrs     = (const float*)d_in[0];
  const float* states    = (const float*)d_in[1];
  const float* rel_attrs = (const float*)d_in[2];
  // d_in[3] = pstep (==2, structural)
  const float* enc_w0  = (const float*)d_in[4];
  const float* enc_b0  = (const float*)d_in[5];
  const float* enc_w1  = (const float*)d_in[6];
  const float* enc_b1  = (const float*)d_in[7];
  const float* rel_w0  = (const float*)d_in[8];
  const float* rel_b0  = (const float*)d_in[9];
  const float* rel_w1  = (const float*)d_in[10];
  const float* rel_b1  = (const float*)d_in[11];
  const float* rp_w    = (const float*)d_in[12];
  const float* rp_b    = (const float*)d_in[13];
  const float* pp_w    = (const float*)d_in[14];
  const float* pp_b    = (const float*)d_in[15];
  const float* pred_w0 = (const float*)d_in[16];
  const float* pred_b0 = (const float*)d_in[17];
  const float* pred_w1 = (const float*)d_in[18];
  const float* pred_b1 = (const float*)d_in[19];
  float* out = (float*)d_out;

  char* ws = (char*)d_ws;
  float* P     = (float*)ws;                                // 64 MB
  float* obj0  = P + (size_t)NROWS_REL * NF;
  float* obj1  = obj0 + NROWS_OBJ * NF;
  float* Q0    = obj1 + NROWS_OBJ * NF;
  float* R0    = Q0 + NROWS_OBJ * NF;
  float* Q1    = R0 + NROWS_OBJ * NF;
  float* R1    = Q1 + NROWS_OBJ * NF;
  float* part1 = R1 + NROWS_OBJ * NF;                       // 2 MB
  float* part2 = part1 + 2 * (size_t)NROWS_OBJ * NF;        // 2 MB
  _Float16* F0 = (_Float16*)(part2 + 2 * (size_t)NROWS_OBJ * NF);
  _Float16* F1 = F0 + F0_ELEMS;
  _Float16* F2 = F1 + F1_ELEMS;

  enc_qr_prep_kernel<<<NROWS_OBJ / 4, 1024, 0, stream>>>(
      attrs, states, enc_w0, enc_b0, enc_w1, enc_b1, rp_w, rp_b,
      rel_w0, rel_w1, F0, F1, F2, obj0, Q0, R0);
  // rel chain ONCE: fused pstep-1 agg + fp32 P store for pstep 2
  rel_agg_store_mfma<<<NROWS_REL / ROWS, 256, 0, stream>>>(
      attrs, states, rel_attrs,
      F0, rel_b0, F1, rel_b1, F2,
      Q0, R0, P, part1);
  upd_qr_kernel<<<NROWS_OBJ / 4, 1024, 0, stream>>>(part1, obj0, pp_w, pp_b,
                                                    rp_w, rp_b, obj1, Q1, R1);
  // pstep 2: float4 streaming P sweep + final update/predictor
  agg_part_kernel<<<dim3(NROWS_OBJ, 2), 256, 0, stream>>>(P, Q1, R1, part2);
  upd_pred_kernel<<<NROWS_OBJ / 4, 1024, 0, stream>>>(part2, obj1, pp_w, pp_b,
                                                      pred_w0, pred_b0,
                                                      pred_w1, pred_b1, out);
}

// Round 14
// 246.117 us; speedup vs baseline: 1.1293x; 1.1293x over previous
//
#include <hip/hip_runtime.h>
#include <hip/hip_bf16.h>
#include <math.h>

// Problem constants (fixed by reference setup_inputs)
#define BB 16
#define NN 64
#define ATTR 4
#define STATE 16
#define RELD 9
#define GG 32
#define NF 256
#define NROWS_OBJ (BB*NN)        // 1024
#define NROWS_REL (BB*NN*NN)     // 65536

typedef _Float16 half8 __attribute__((ext_vector_type(8)));
typedef float  floatx4 __attribute__((ext_vector_type(4)));
typedef unsigned short ushort_t;

// fp16 split: x ~= h + l, |x-(h+l)| ~ 2^-22 |x| (A-operand use only)
__device__ __forceinline__ void split2h(float x, _Float16& h, _Float16& l) {
  h = (_Float16)x;
  l = (_Float16)(x - (float)h);
}

#define F0_ELEMS (2 * 16 * 64 * 8)   // 16384
#define F1_ELEMS (8 * 16 * 64 * 8)   // 65536
#define F_TOTAL  (F0_ELEMS + 2 * F1_ELEMS)

// ---------------------------------------------------------------------------
// k-split GEMM partial: thread (kseg=tid>>8, rsel=(tid>>6)&3, cg=tid&63)
// accumulates 4 cols (c4=cg*4) of row rsel over k in [kseg*64, kseg*64+64).
// float4 weight loads (wave: 64 lanes x 16B = 1KB contiguous, 16 lines/inst),
// unroll 8 -> 8 latency batches instead of 32 (HBM-cold weights after the
// harness's 80MB d_ws poison evict L2 every replay — R12 counter evidence:
// upd_qr 58.7us @ 152GB/s, pure latency serialization).
// Result goes to red[(kseg*4+rsel)*NF + c4] (16KB LDS); reduce 4-way after.
// ---------------------------------------------------------------------------
__device__ __forceinline__ float4 gemm4_k64(const float* __restrict__ W,
                                            const float* A,
                                            int kseg, int rsel, int c4)
{
  float4 p = make_float4(0.f, 0.f, 0.f, 0.f);
  int k0 = kseg * 64;
#pragma unroll 8
  for (int k = 0; k < 64; ++k) {
    float4 w = *(const float4*)(W + (size_t)(k0 + k) * NF + c4);
    float a = A[rsel * NF + k0 + k];
    p.x += a * w.x; p.y += a * w.y; p.z += a * w.z; p.w += a * w.w;
  }
  return p;
}

// ---------------------------------------------------------------------------
// Fused encoder + Q/R + weight-fragment prep (k-split GEMM loops).
// ---------------------------------------------------------------------------
__global__ __launch_bounds__(1024) void enc_qr_prep_kernel(
    const float* __restrict__ attrs, const float* __restrict__ states,
    const float* __restrict__ w0, const float* __restrict__ b0,
    const float* __restrict__ w1, const float* __restrict__ b1,
    const float* __restrict__ rpw, const float* __restrict__ rpb,
    const float* __restrict__ rel_w0, const float* __restrict__ rel_w1,
    _Float16* __restrict__ F0, _Float16* __restrict__ F1,
    _Float16* __restrict__ F2,
    float* __restrict__ obj, float* __restrict__ Q, float* __restrict__ R)
{
  int tid = threadIdx.x;
  for (int idx = blockIdx.x * 1024 + tid; idx < F_TOTAL; idx += 256 * 1024) {
    if (idx < F0_ELEMS) {
      int j = idx & 7, lane = (idx >> 3) & 63, g = (idx >> 9) & 15, s = idx >> 13;
      int k = s * 32 + (lane >> 4) * 8 + j, n = g * 16 + (lane & 15);
      float v = (k < 33) ? rel_w0[k * NF + n] : 0.f;
      F0[idx] = (_Float16)v;
    } else if (idx < F0_ELEMS + F1_ELEMS) {
      int t = idx - F0_ELEMS;
      int j = t & 7, lane = (t >> 3) & 63, g = (t >> 9) & 15, s = t >> 13;
      int k = s * 32 + (lane >> 4) * 8 + j, n = g * 16 + (lane & 15);
      F1[t] = (_Float16)rel_w1[k * NF + n];
    } else {
      int t = idx - (F0_ELEMS + F1_ELEMS);
      int j = t & 7, lane = (t >> 3) & 63, g = (t >> 9) & 15, s = t >> 13;
      int k = s * 32 + (lane >> 4) * 8 + j, n = g * 16 + (lane & 15);
      F2[t] = (_Float16)rpw[k * NF + n];
    }
  }
  __shared__ float X[4 * 20];
  __shared__ float H[4 * NF];
  __shared__ float O[4 * NF];
  __shared__ __align__(16) float red[16 * NF];
  int row0 = blockIdx.x * 4;
  if (tid < 80) {
    int r = tid / 20, k = tid % 20;
    int m = row0 + r;
    X[tid] = (k < ATTR) ? attrs[m * ATTR + k] : states[m * STATE + (k - ATTR)];
  }
  __syncthreads();
  int r = tid >> 8, c = tid & 255;
  int kseg = tid >> 8, rsel = (tid >> 6) & 3, c4 = (tid & 63) * 4;
  // stage 1: K=20 (LDS-only, cheap)
  {
    float a = b0[c];
#pragma unroll
    for (int k = 0; k < 20; ++k) a += X[r * 20 + k] * w0[k * NF + c];
    H[r * NF + c] = fmaxf(a, 0.f);
  }
  __syncthreads();
  // stage 2: O = ReLU(H @ w1 + b1)
  {
    float4 p = gemm4_k64(w1, H, kseg, rsel, c4);
    *(float4*)(&red[(kseg * 4 + rsel) * NF + c4]) = p;
  }
  __syncthreads();
  {
    float a = b1[c] + red[(0 + r) * NF + c] + red[(4 + r) * NF + c]
            + red[(8 + r) * NF + c] + red[(12 + r) * NF + c];
    a = fmaxf(a, 0.f);
    O[r * NF + c] = a;
    obj[(row0 + r) * NF + c] = a;
  }
  __syncthreads();
  // Q = O @ rpw[256:512] + rpb
  {
    float4 p = gemm4_k64(rpw + 256 * NF, O, kseg, rsel, c4);
    *(float4*)(&red[(kseg * 4 + rsel) * NF + c4]) = p;
  }
  __syncthreads();
  Q[(row0 + r) * NF + c] = rpb[c] + red[(0 + r) * NF + c] + red[(4 + r) * NF + c]
                         + red[(8 + r) * NF + c] + red[(12 + r) * NF + c];
  __syncthreads();
  // R = O @ rpw[512:768]
  {
    float4 p = gemm4_k64(rpw + 512 * NF, O, kseg, rsel, c4);
    *(float4*)(&red[(kseg * 4 + rsel) * NF + c4]) = p;
  }
  __syncthreads();
  R[(row0 + r) * NF + c] = red[(0 + r) * NF + c] + red[(4 + r) * NF + c]
                         + red[(8 + r) * NF + c] + red[(12 + r) * NF + c];
}

// ---------------------------------------------------------------------------
// Relation chain, fp16 A-split x B-single MFMA (FROZEN from R10: ~59us,
// absmax 0.0156): run ONCE, stage-3 P-tile in regs -> fp32 P store + fused
// pstep-1 aggregation epilogue.
// ---------------------------------------------------------------------------
#define ROWS 32
#define NRT 2
#define HSTR 264
#define XSTR 72

__global__ __launch_bounds__(256, 4) void rel_agg_store_mfma(
    const float* __restrict__ attrs, const float* __restrict__ states,
    const float* __restrict__ rel_attrs,
    const _Float16* __restrict__ F0, const float* __restrict__ b0,
    const _Float16* __restrict__ F1, const float* __restrict__ b1,
    const _Float16* __restrict__ F2,
    const float* __restrict__ Q, const float* __restrict__ R,
    float* __restrict__ P, float* __restrict__ part)
{
  __shared__ __align__(16) _Float16 S[2 * ROWS * HSTR];   // 33792 B
  _Float16* Hh = S;
  _Float16* Hl = S + ROWS * HSTR;
  _Float16* Xh = Hh;   // X aliased onto H (dead after stage 1)
  _Float16* Xl = Hl;

  int tid  = threadIdx.x;
  int wave = tid >> 6;
  int lane = tid & 63;
  int quad = lane >> 4;
  int l16  = lane & 15;
  int row0 = blockIdx.x * ROWS;

  for (int idx = tid; idx < ROWS * 64; idx += 256) {
    int r = idx >> 6, k = idx & 63;
    int grow = row0 + r;
    int j = grow & 63, i = (grow >> 6) & 63, b = grow >> 12;
    float v = 0.f;
    if (k < RELD)                     v = rel_attrs[(size_t)grow * RELD + k];
    else if (k < RELD + STATE)        v = states[(b * NN + i) * STATE + (k - RELD)]
                                        - states[(b * NN + j) * STATE + (k - RELD)];
    else if (k < RELD + STATE + ATTR) v = attrs[(b * NN + i) * ATTR + (k - RELD - STATE)];
    else if (k < 33)                  v = attrs[(b * NN + j) * ATTR + (k - RELD - STATE - ATTR)];
    _Float16 h, l; split2h(v, h, l);
    Xh[r * XSTR + k] = h;
    Xl[r * XSTR + k] = l;
  }
  __syncthreads();

  floatx4 acc[NRT][4];

#define ZERO_ACC() do { \
  _Pragma("unroll") for (int rt = 0; rt < NRT; ++rt) \
  _Pragma("unroll") for (int ct = 0; ct < 4; ++ct) acc[rt][ct] = (floatx4)(0.f); } while (0)

#define STAGE(Sn, AH, AL, ASTR, BF) do { \
  half8 ah[2][NRT], al[2][NRT], bf[2][4]; \
  _Pragma("unroll") for (int ct = 0; ct < 4; ++ct) \
    bf[0][ct] = *(const half8*)((BF) + (size_t)((wave * 4 + ct) * 64 + lane) * 8); \
  _Pragma("unroll") for (int rt = 0; rt < NRT; ++rt) { \
    ah[0][rt] = *(const half8*)(&(AH)[(rt * 16 + l16) * (ASTR) + quad * 8]); \
    al[0][rt] = *(const half8*)(&(AL)[(rt * 16 + l16) * (ASTR) + quad * 8]); } \
  _Pragma("unroll") \
  for (int s = 0; s < (Sn); ++s) { \
    int cur = s & 1, nxt = cur ^ 1; \
    if (s + 1 < (Sn)) { \
      _Pragma("unroll") for (int ct = 0; ct < 4; ++ct) \
        bf[nxt][ct] = *(const half8*)((BF) + (size_t)(((s + 1) * 16 + wave * 4 + ct) * 64 + lane) * 8); \
      _Pragma("unroll") for (int rt = 0; rt < NRT; ++rt) { \
        ah[nxt][rt] = *(const half8*)(&(AH)[(rt * 16 + l16) * (ASTR) + (s + 1) * 32 + quad * 8]); \
        al[nxt][rt] = *(const half8*)(&(AL)[(rt * 16 + l16) * (ASTR) + (s + 1) * 32 + quad * 8]); } } \
    _Pragma("unroll") for (int rt = 0; rt < NRT; ++rt) \
    _Pragma("unroll") for (int ct = 0; ct < 4; ++ct) { \
      acc[rt][ct] = __builtin_amdgcn_mfma_f32_16x16x32_f16(ah[cur][rt], bf[cur][ct], acc[rt][ct], 0, 0, 0); \
      acc[rt][ct] = __builtin_amdgcn_mfma_f32_16x16x32_f16(al[cur][rt], bf[cur][ct], acc[rt][ct], 0, 0, 0); } \
  } } while (0)

  // ---- stage 1: H = ReLU(X @ W0 + b0), K=64 (padded)
  ZERO_ACC();
  STAGE(2, Xh, Xl, XSTR, F0);
  __syncthreads();  // X reads done before H overwrites the aliased region
#pragma unroll
  for (int ct = 0; ct < 4; ++ct) {
    int col = wave * 64 + ct * 16 + l16;
    float bias = b0[col];
#pragma unroll
    for (int rt = 0; rt < NRT; ++rt)
#pragma unroll
      for (int r = 0; r < 4; ++r) {
        int row = rt * 16 + quad * 4 + r;
        float h = fmaxf(acc[rt][ct][r] + bias, 0.f);
        split2h(h, Hh[row * HSTR + col], Hl[row * HSTR + col]);
      }
  }
  __syncthreads();

  // ---- stage 2: E = ReLU(H @ W1 + b1), K=256
  ZERO_ACC();
  STAGE(8, Hh, Hl, HSTR, F1);
  __syncthreads();
#pragma unroll
  for (int ct = 0; ct < 4; ++ct) {
    int col = wave * 64 + ct * 16 + l16;
    float bias = b1[col];
#pragma unroll
    for (int rt = 0; rt < NRT; ++rt)
#pragma unroll
      for (int r = 0; r < 4; ++r) {
        int row = rt * 16 + quad * 4 + r;
        float e = fmaxf(acc[rt][ct][r] + bias, 0.f);
        split2h(e, Hh[row * HSTR + col], Hl[row * HSTR + col]);
      }
  }
  __syncthreads();

  // ---- stage 3: P-tile in registers (K=256)
  ZERO_ACC();
  STAGE(8, Hh, Hl, HSTR, F2);

  // ---- store P fp32 (pstep 2 reads it via agg_part)
#pragma unroll
  for (int ct = 0; ct < 4; ++ct) {
    int col = wave * 64 + ct * 16 + l16;
#pragma unroll
    for (int rt = 0; rt < NRT; ++rt)
#pragma unroll
      for (int r = 0; r < 4; ++r) {
        int row = rt * 16 + quad * 4 + r;
        P[(size_t)(row0 + row) * NF + col] = acc[rt][ct][r];
      }
  }
  __syncthreads();                       // all E reads done — LDS reusable

  // ---- fused pstep-1 aggregation epilogue
  {
    float* Rs = (float*)S;               // 32 x 256 fp32 R-tile (32KB)
    int bi    = row0 >> 6;
    int jbase = row0 & 63;               // 0 or 32
    int b     = row0 >> 12;
    for (int idx = tid; idx < ROWS * NF; idx += 256) {
      int rr = idx >> 8, cc = idx & 255;
      Rs[idx] = R[(size_t)(b * NN + jbase + rr) * NF + cc];
    }
    __syncthreads();
#pragma unroll
    for (int ct = 0; ct < 4; ++ct) {
      int col = wave * 64 + ct * 16 + l16;
      float q = Q[bi * NF + col];
      float s = 0.f;
#pragma unroll
      for (int rt = 0; rt < NRT; ++rt)
#pragma unroll
        for (int r = 0; r < 4; ++r) {
          int row = rt * 16 + quad * 4 + r;
          s += fmaxf(acc[rt][ct][r] + q + Rs[row * NF + col], 0.f);
        }
      s += __shfl_xor(s, 16, 64);        // quad butterfly: rows 0..31 summed
      s += __shfl_xor(s, 32, 64);
      if (quad == 0)
        part[((size_t)bi * 2 + (jbase >> 5)) * NF + col] = s;
    }
  }
#undef ZERO_ACC
#undef STAGE
}

// ---------------------------------------------------------------------------
// upd_qr with k-split GEMMs: G = part1 halves; obj' = ReLU([obj,G]@pp+b);
// Q',R' from obj'.
// ---------------------------------------------------------------------------
__global__ __launch_bounds__(1024) void upd_qr_kernel(
    const float* __restrict__ part, const float* __restrict__ obj,
    const float* __restrict__ ppw, const float* __restrict__ ppb,
    const float* __restrict__ rpw, const float* __restrict__ rpb,
    float* __restrict__ obj_out, float* __restrict__ Qo, float* __restrict__ Ro)
{
  __shared__ float A[4 * NF];
  __shared__ float G[4 * NF];
  __shared__ __align__(16) float red[16 * NF];
  int tid = threadIdx.x;
  int row0 = blockIdx.x * 4;
  int r = tid >> 8, c = tid & 255;
  int kseg = tid >> 8, rsel = (tid >> 6) & 3, c4 = (tid & 63) * 4;
  A[r * NF + c] = obj[(row0 + r) * NF + c];
  G[r * NF + c] = part[((size_t)(row0 + r) * 2 + 0) * NF + c]
                + part[((size_t)(row0 + r) * 2 + 1) * NF + c];
  __syncthreads();
  {
    float4 p = gemm4_k64(ppw, A, kseg, rsel, c4);
    float4 q = gemm4_k64(ppw + NF * NF, G, kseg, rsel, c4);
    p.x += q.x; p.y += q.y; p.z += q.z; p.w += q.w;
    *(float4*)(&red[(kseg * 4 + rsel) * NF + c4]) = p;
  }
  __syncthreads();
  {
    float a = ppb[c] + red[(0 + r) * NF + c] + red[(4 + r) * NF + c]
            + red[(8 + r) * NF + c] + red[(12 + r) * NF + c];
    float o = fmaxf(a, 0.f);
    A[r * NF + c] = o;                 // safe: all gemm4 A reads pre-barrier
    obj_out[(row0 + r) * NF + c] = o;
  }
  __syncthreads();
  {
    float4 p = gemm4_k64(rpw + 256 * NF, A, kseg, rsel, c4);
    *(float4*)(&red[(kseg * 4 + rsel) * NF + c4]) = p;
  }
  __syncthreads();
  Qo[(row0 + r) * NF + c] = rpb[c] + red[(0 + r) * NF + c] + red[(4 + r) * NF + c]
                          + red[(8 + r) * NF + c] + red[(12 + r) * NF + c];
  __syncthreads();
  {
    float4 p = gemm4_k64(rpw + 512 * NF, A, kseg, rsel, c4);
    *(float4*)(&red[(kseg * 4 + rsel) * NF + c4]) = p;
  }
  __syncthreads();
  Ro[(row0 + r) * NF + c] = red[(0 + r) * NF + c] + red[(4 + r) * NF + c]
                          + red[(8 + r) * NF + c] + red[(12 + r) * NF + c];
}

// ---------------------------------------------------------------------------
// agg_part v2 (frozen): float4 streaming sweep of P. grid (1024,2) x 256.
// ---------------------------------------------------------------------------
__global__ __launch_bounds__(256) void agg_part_kernel(
    const float* __restrict__ P, const float* __restrict__ Q,
    const float* __restrict__ R, float* __restrict__ part)
{
  __shared__ float red[4 * NF];
  int bi = blockIdx.x;
  int jh = blockIdx.y;
  int tid = threadIdx.x;
  int c4 = (tid & 63) * 4;
  int jq = tid >> 6;
  int b = bi >> 6;
  float4 q4 = *(const float4*)(Q + bi * NF + c4);
  const float* Pb = P + ((size_t)bi * NN + jh * 32 + jq * 8) * NF + c4;
  const float* Rb = R + (size_t)(b * NN + jh * 32 + jq * 8) * NF + c4;
  float4 s = make_float4(0.f, 0.f, 0.f, 0.f);
#pragma unroll
  for (int j = 0; j < 8; ++j) {
    float4 p  = *(const float4*)(Pb + (size_t)j * NF);
    float4 rv = *(const float4*)(Rb + (size_t)j * NF);
    s.x += fmaxf(p.x + q4.x + rv.x, 0.f);
    s.y += fmaxf(p.y + q4.y + rv.y, 0.f);
    s.z += fmaxf(p.z + q4.z + rv.z, 0.f);
    s.w += fmaxf(p.w + q4.w + rv.w, 0.f);
  }
  *(float4*)(&red[jq * NF + c4]) = s;
  __syncthreads();
  if (jq == 0) {
    float4 t0 = *(const float4*)(&red[0 * NF + c4]);
    float4 t1 = *(const float4*)(&red[1 * NF + c4]);
    float4 t2 = *(const float4*)(&red[2 * NF + c4]);
    float4 t3 = *(const float4*)(&red[3 * NF + c4]);
    float4 o;
    o.x = t0.x + t1.x + t2.x + t3.x;
    o.y = t0.y + t1.y + t2.y + t3.y;
    o.z = t0.z + t1.z + t2.z + t3.z;
    o.w = t0.w + t1.w + t2.w + t3.w;
    *(float4*)(part + ((size_t)bi * 2 + jh) * NF + c4) = o;
  }
}

// ---------------------------------------------------------------------------
// Final update + predictor with k-split GEMMs; pred's 256x32 loop split 8-way.
// ---------------------------------------------------------------------------
__global__ __launch_bounds__(1024) void upd_pred_kernel(
    const float* __restrict__ part, const float* __restrict__ obj,
    const float* __restrict__ ppw, const float* __restrict__ ppb,
    const float* __restrict__ w0, const float* __restrict__ b0,
    const float* __restrict__ w1, const float* __restrict__ b1,
    float* __restrict__ out)
{
  __shared__ float A[4 * NF];
  __shared__ float G[4 * NF];
  __shared__ __align__(16) float red[16 * NF];
  int tid = threadIdx.x;
  int row0 = blockIdx.x * 4;
  int r = tid >> 8, c = tid & 255;
  int kseg = tid >> 8, rsel = (tid >> 6) & 3, c4 = (tid & 63) * 4;
  A[r * NF + c] = obj[(row0 + r) * NF + c];
  G[r * NF + c] = part[((size_t)(row0 + r) * 2 + 0) * NF + c]
                + part[((size_t)(row0 + r) * 2 + 1) * NF + c];
  __syncthreads();
  {
    float4 p = gemm4_k64(ppw, A, kseg, rsel, c4);
    float4 q = gemm4_k64(ppw + NF * NF, G, kseg, rsel, c4);
    p.x += q.x; p.y += q.y; p.z += q.z; p.w += q.w;
    *(float4*)(&red[(kseg * 4 + rsel) * NF + c4]) = p;
  }
  __syncthreads();
  {
    float a = ppb[c] + red[(0 + r) * NF + c] + red[(4 + r) * NF + c]
            + red[(8 + r) * NF + c] + red[(12 + r) * NF + c];
    A[r * NF + c] = fmaxf(a, 0.f);     // obj2
  }
  __syncthreads();
  {
    float4 p = gemm4_k64(w0, A, kseg, rsel, c4);
    *(float4*)(&red[(kseg * 4 + rsel) * NF + c4]) = p;
  }
  __syncthreads();
  {
    float a = b0[c] + red[(0 + r) * NF + c] + red[(4 + r) * NF + c]
            + red[(8 + r) * NF + c] + red[(12 + r) * NF + c];
    G[r * NF + c] = fmaxf(a, 0.f);     // T (G reads done at pp barrier)
  }
  __syncthreads();
  // out = tanh(T @ w1 + b1): 8-way k-split over 1024 threads
  {
    int ks8 = tid >> 7, rr = (tid >> 5) & 3, g = tid & 31;
    float s = 0.f;
#pragma unroll 8
    for (int k = 0; k < 32; ++k)
      s += G[rr * NF + ks8 * 32 + k] * w1[(ks8 * 32 + k) * GG + g];
    red[tid] = s;
  }
  __syncthreads();
  if (tid < 4 * GG) {
    int rr = tid >> 5, g = tid & 31;
    float a = b1[g];
#pragma unroll
    for (int ks = 0; ks < 8; ++ks) a += red[ks * 128 + tid];
    out[(row0 + rr) * GG + g] = tanhf(a);
  }
}

extern "C" void kernel_launch(void* const* d_in, const int* in_sizes, int n_in,
                              void* d_out, int out_size, void* d_ws, size_t ws_size,
                              hipStream_t stream)
{
  const float* attrs     = (const float*)d_in[0];
  const float* states    = (const float*)d_in[1];
  const float* rel_attrs = (const float*)d_in[2];
  // d_in[3] = pstep (==2, structural)
  const float* enc_w0  = (const float*)d_in[4];
  const float* enc_b0  = (const float*)d_in[5];
  const float* enc_w1  = (const float*)d_in[6];
  const float* enc_b1  = (const float*)d_in[7];
  const float* rel_w0  = (const float*)d_in[8];
  const float* rel_b0  = (const float*)d_in[9];
  const float* rel_w1  = (const float*)d_in[10];
  const float* rel_b1  = (const float*)d_in[11];
  const float* rp_w    = (const float*)d_in[12];
  const float* rp_b    = (const float*)d_in[13];
  const float* pp_w    = (const float*)d_in[14];
  const float* pp_b    = (const float*)d_in[15];
  const float* pred_w0 = (const float*)d_in[16];
  const float* pred_b0 = (const float*)d_in[17];
  const float* pred_w1 = (const float*)d_in[18];
  const float* pred_b1 = (const float*)d_in[19];
  float* out = (float*)d_out;

  char* ws = (char*)d_ws;
  float* P     = (float*)ws;                                // 64 MB
  float* obj0  = P + (size_t)NROWS_REL * NF;
  float* obj1  = obj0 + NROWS_OBJ * NF;
  float* Q0    = obj1 + NROWS_OBJ * NF;
  float* R0    = Q0 + NROWS_OBJ * NF;
  float* Q1    = R0 + NROWS_OBJ * NF;
  float* R1    = Q1 + NROWS_OBJ * NF;
  float* part1 = R1 + NROWS_OBJ * NF;                       // 2 MB
  float* part2 = part1 + 2 * (size_t)NROWS_OBJ * NF;        // 2 MB
  _Float16* F0 = (_Float16*)(part2 + 2 * (size_t)NROWS_OBJ * NF);
  _Float16* F1 = F0 + F0_ELEMS;
  _Float16* F2 = F1 + F1_ELEMS;

  enc_qr_prep_kernel<<<NROWS_OBJ / 4, 1024, 0, stream>>>(
      attrs, states, enc_w0, enc_b0, enc_w1, enc_b1, rp_w, rp_b,
      rel_w0, rel_w1, F0, F1, F2, obj0, Q0, R0);
  // rel chain ONCE: fused pstep-1 agg + fp32 P store for pstep 2
  rel_agg_store_mfma<<<NROWS_REL / ROWS, 256, 0, stream>>>(
      attrs, states, rel_attrs,
      F0, rel_b0, F1, rel_b1, F2,
      Q0, R0, P, part1);
  upd_qr_kernel<<<NROWS_OBJ / 4, 1024, 0, stream>>>(part1, obj0, pp_w, pp_b,
                                                    rp_w, rp_b, obj1, Q1, R1);
  // pstep 2: float4 streaming P sweep + final update/predictor
  agg_part_kernel<<<dim3(NROWS_OBJ, 2), 256, 0, stream>>>(P, Q1, R1, part2);
  upd_pred_kernel<<<NROWS_OBJ / 4, 1024, 0, stream>>>(part2, obj1, pp_w, pp_b,
                                                      pred_w0, pred_b0,
                                                      pred_w1, pred_b1, out);
}

// Round 15
// 235.698 us; speedup vs baseline: 1.1792x; 1.0442x over previous
//
#include <hip/hip_runtime.h>
#include <hip/hip_bf16.h>
#include <math.h>

// Problem constants (fixed by reference setup_inputs)
#define BB 16
#define NN 64
#define ATTR 4
#define STATE 16
#define RELD 9
#define GG 32
#define NF 256
#define NROWS_OBJ (BB*NN)        // 1024
#define NROWS_REL (BB*NN*NN)     // 65536

typedef _Float16 half8 __attribute__((ext_vector_type(8)));
typedef _Float16 half4 __attribute__((ext_vector_type(4)));
typedef float  floatx4 __attribute__((ext_vector_type(4)));
typedef unsigned short ushort_t;

// fp16 split: x ~= h + l, |x-(h+l)| ~ 2^-22 |x| (A-operand use only)
__device__ __forceinline__ void split2h(float x, _Float16& h, _Float16& l) {
  h = (_Float16)x;
  l = (_Float16)(x - (float)h);
}

#define F0_ELEMS (2 * 16 * 64 * 8)   // 16384
#define F1_ELEMS (8 * 16 * 64 * 8)   // 65536
#define F_TOTAL  (F0_ELEMS + 2 * F1_ELEMS)

// ---------------------------------------------------------------------------
// k-split GEMM partial (R13, frozen): thread (kseg, rsel, c4) accumulates 4
// cols over 64 k's; float4 weight loads, 8 latency batches.
// ---------------------------------------------------------------------------
__device__ __forceinline__ float4 gemm4_k64(const float* __restrict__ W,
                                            const float* A,
                                            int kseg, int rsel, int c4)
{
  float4 p = make_float4(0.f, 0.f, 0.f, 0.f);
  int k0 = kseg * 64;
#pragma unroll 8
  for (int k = 0; k < 64; ++k) {
    float4 w = *(const float4*)(W + (size_t)(k0 + k) * NF + c4);
    float a = A[rsel * NF + k0 + k];
    p.x += a * w.x; p.y += a * w.y; p.z += a * w.z; p.w += a * w.w;
  }
  return p;
}

// ---------------------------------------------------------------------------
// Fused encoder + Q/R + weight-fragment prep (R13, frozen).
// ---------------------------------------------------------------------------
__global__ __launch_bounds__(1024) void enc_qr_prep_kernel(
    const float* __restrict__ attrs, const float* __restrict__ states,
    const float* __restrict__ w0, const float* __restrict__ b0,
    const float* __restrict__ w1, const float* __restrict__ b1,
    const float* __restrict__ rpw, const float* __restrict__ rpb,
    const float* __restrict__ rel_w0, const float* __restrict__ rel_w1,
    _Float16* __restrict__ F0, _Float16* __restrict__ F1,
    _Float16* __restrict__ F2,
    float* __restrict__ obj, float* __restrict__ Q, float* __restrict__ R)
{
  int tid = threadIdx.x;
  for (int idx = blockIdx.x * 1024 + tid; idx < F_TOTAL; idx += 256 * 1024) {
    if (idx < F0_ELEMS) {
      int j = idx & 7, lane = (idx >> 3) & 63, g = (idx >> 9) & 15, s = idx >> 13;
      int k = s * 32 + (lane >> 4) * 8 + j, n = g * 16 + (lane & 15);
      float v = (k < 33) ? rel_w0[k * NF + n] : 0.f;
      F0[idx] = (_Float16)v;
    } else if (idx < F0_ELEMS + F1_ELEMS) {
      int t = idx - F0_ELEMS;
      int j = t & 7, lane = (t >> 3) & 63, g = (t >> 9) & 15, s = t >> 13;
      int k = s * 32 + (lane >> 4) * 8 + j, n = g * 16 + (lane & 15);
      F1[t] = (_Float16)rel_w1[k * NF + n];
    } else {
      int t = idx - (F0_ELEMS + F1_ELEMS);
      int j = t & 7, lane = (t >> 3) & 63, g = (t >> 9) & 15, s = t >> 13;
      int k = s * 32 + (lane >> 4) * 8 + j, n = g * 16 + (lane & 15);
      F2[t] = (_Float16)rpw[k * NF + n];
    }
  }
  __shared__ float X[4 * 20];
  __shared__ float H[4 * NF];
  __shared__ float O[4 * NF];
  __shared__ __align__(16) float red[16 * NF];
  int row0 = blockIdx.x * 4;
  if (tid < 80) {
    int r = tid / 20, k = tid % 20;
    int m = row0 + r;
    X[tid] = (k < ATTR) ? attrs[m * ATTR + k] : states[m * STATE + (k - ATTR)];
  }
  __syncthreads();
  int r = tid >> 8, c = tid & 255;
  int kseg = tid >> 8, rsel = (tid >> 6) & 3, c4 = (tid & 63) * 4;
  {
    float a = b0[c];
#pragma unroll
    for (int k = 0; k < 20; ++k) a += X[r * 20 + k] * w0[k * NF + c];
    H[r * NF + c] = fmaxf(a, 0.f);
  }
  __syncthreads();
  {
    float4 p = gemm4_k64(w1, H, kseg, rsel, c4);
    *(float4*)(&red[(kseg * 4 + rsel) * NF + c4]) = p;
  }
  __syncthreads();
  {
    float a = b1[c] + red[(0 + r) * NF + c] + red[(4 + r) * NF + c]
            + red[(8 + r) * NF + c] + red[(12 + r) * NF + c];
    a = fmaxf(a, 0.f);
    O[r * NF + c] = a;
    obj[(row0 + r) * NF + c] = a;
  }
  __syncthreads();
  {
    float4 p = gemm4_k64(rpw + 256 * NF, O, kseg, rsel, c4);
    *(float4*)(&red[(kseg * 4 + rsel) * NF + c4]) = p;
  }
  __syncthreads();
  Q[(row0 + r) * NF + c] = rpb[c] + red[(0 + r) * NF + c] + red[(4 + r) * NF + c]
                         + red[(8 + r) * NF + c] + red[(12 + r) * NF + c];
  __syncthreads();
  {
    float4 p = gemm4_k64(rpw + 512 * NF, O, kseg, rsel, c4);
    *(float4*)(&red[(kseg * 4 + rsel) * NF + c4]) = p;
  }
  __syncthreads();
  R[(row0 + r) * NF + c] = red[(0 + r) * NF + c] + red[(4 + r) * NF + c]
                         + red[(8 + r) * NF + c] + red[(12 + r) * NF + c];
}

// ---------------------------------------------------------------------------
// Relation chain, fp16 A-split x B-single MFMA (structure frozen from R10).
// CHANGE R14: P stored fp16 (pstep-2 read path only; pstep-1 agg uses the
// exact fp32 register acc). Halves P HBM traffic (64->32 MB each way).
// ---------------------------------------------------------------------------
#define ROWS 32
#define NRT 2
#define HSTR 264
#define XSTR 72

__global__ __launch_bounds__(256, 4) void rel_agg_store_mfma(
    const float* __restrict__ attrs, const float* __restrict__ states,
    const float* __restrict__ rel_attrs,
    const _Float16* __restrict__ F0, const float* __restrict__ b0,
    const _Float16* __restrict__ F1, const float* __restrict__ b1,
    const _Float16* __restrict__ F2,
    const float* __restrict__ Q, const float* __restrict__ R,
    _Float16* __restrict__ P, float* __restrict__ part)
{
  __shared__ __align__(16) _Float16 S[2 * ROWS * HSTR];   // 33792 B
  _Float16* Hh = S;
  _Float16* Hl = S + ROWS * HSTR;
  _Float16* Xh = Hh;   // X aliased onto H (dead after stage 1)
  _Float16* Xl = Hl;

  int tid  = threadIdx.x;
  int wave = tid >> 6;
  int lane = tid & 63;
  int quad = lane >> 4;
  int l16  = lane & 15;
  int row0 = blockIdx.x * ROWS;

  for (int idx = tid; idx < ROWS * 64; idx += 256) {
    int r = idx >> 6, k = idx & 63;
    int grow = row0 + r;
    int j = grow & 63, i = (grow >> 6) & 63, b = grow >> 12;
    float v = 0.f;
    if (k < RELD)                     v = rel_attrs[(size_t)grow * RELD + k];
    else if (k < RELD + STATE)        v = states[(b * NN + i) * STATE + (k - RELD)]
                                        - states[(b * NN + j) * STATE + (k - RELD)];
    else if (k < RELD + STATE + ATTR) v = attrs[(b * NN + i) * ATTR + (k - RELD - STATE)];
    else if (k < 33)                  v = attrs[(b * NN + j) * ATTR + (k - RELD - STATE - ATTR)];
    _Float16 h, l; split2h(v, h, l);
    Xh[r * XSTR + k] = h;
    Xl[r * XSTR + k] = l;
  }
  __syncthreads();

  floatx4 acc[NRT][4];

#define ZERO_ACC() do { \
  _Pragma("unroll") for (int rt = 0; rt < NRT; ++rt) \
  _Pragma("unroll") for (int ct = 0; ct < 4; ++ct) acc[rt][ct] = (floatx4)(0.f); } while (0)

#define STAGE(Sn, AH, AL, ASTR, BF) do { \
  half8 ah[2][NRT], al[2][NRT], bf[2][4]; \
  _Pragma("unroll") for (int ct = 0; ct < 4; ++ct) \
    bf[0][ct] = *(const half8*)((BF) + (size_t)((wave * 4 + ct) * 64 + lane) * 8); \
  _Pragma("unroll") for (int rt = 0; rt < NRT; ++rt) { \
    ah[0][rt] = *(const half8*)(&(AH)[(rt * 16 + l16) * (ASTR) + quad * 8]); \
    al[0][rt] = *(const half8*)(&(AL)[(rt * 16 + l16) * (ASTR) + quad * 8]); } \
  _Pragma("unroll") \
  for (int s = 0; s < (Sn); ++s) { \
    int cur = s & 1, nxt = cur ^ 1; \
    if (s + 1 < (Sn)) { \
      _Pragma("unroll") for (int ct = 0; ct < 4; ++ct) \
        bf[nxt][ct] = *(const half8*)((BF) + (size_t)(((s + 1) * 16 + wave * 4 + ct) * 64 + lane) * 8); \
      _Pragma("unroll") for (int rt = 0; rt < NRT; ++rt) { \
        ah[nxt][rt] = *(const half8*)(&(AH)[(rt * 16 + l16) * (ASTR) + (s + 1) * 32 + quad * 8]); \
        al[nxt][rt] = *(const half8*)(&(AL)[(rt * 16 + l16) * (ASTR) + (s + 1) * 32 + quad * 8]); } } \
    _Pragma("unroll") for (int rt = 0; rt < NRT; ++rt) \
    _Pragma("unroll") for (int ct = 0; ct < 4; ++ct) { \
      acc[rt][ct] = __builtin_amdgcn_mfma_f32_16x16x32_f16(ah[cur][rt], bf[cur][ct], acc[rt][ct], 0, 0, 0); \
      acc[rt][ct] = __builtin_amdgcn_mfma_f32_16x16x32_f16(al[cur][rt], bf[cur][ct], acc[rt][ct], 0, 0, 0); } \
  } } while (0)

  // ---- stage 1: H = ReLU(X @ W0 + b0), K=64 (padded)
  ZERO_ACC();
  STAGE(2, Xh, Xl, XSTR, F0);
  __syncthreads();  // X reads done before H overwrites the aliased region
#pragma unroll
  for (int ct = 0; ct < 4; ++ct) {
    int col = wave * 64 + ct * 16 + l16;
    float bias = b0[col];
#pragma unroll
    for (int rt = 0; rt < NRT; ++rt)
#pragma unroll
      for (int r = 0; r < 4; ++r) {
        int row = rt * 16 + quad * 4 + r;
        float h = fmaxf(acc[rt][ct][r] + bias, 0.f);
        split2h(h, Hh[row * HSTR + col], Hl[row * HSTR + col]);
      }
  }
  __syncthreads();

  // ---- stage 2: E = ReLU(H @ W1 + b1), K=256
  ZERO_ACC();
  STAGE(8, Hh, Hl, HSTR, F1);
  __syncthreads();
#pragma unroll
  for (int ct = 0; ct < 4; ++ct) {
    int col = wave * 64 + ct * 16 + l16;
    float bias = b1[col];
#pragma unroll
    for (int rt = 0; rt < NRT; ++rt)
#pragma unroll
      for (int r = 0; r < 4; ++r) {
        int row = rt * 16 + quad * 4 + r;
        float e = fmaxf(acc[rt][ct][r] + bias, 0.f);
        split2h(e, Hh[row * HSTR + col], Hl[row * HSTR + col]);
      }
  }
  __syncthreads();

  // ---- stage 3: P-tile in registers (K=256)
  ZERO_ACC();
  STAGE(8, Hh, Hl, HSTR, F2);

  // ---- store P fp16 (pstep 2 reads it via agg_part; pstep-1 uses fp32 acc)
#pragma unroll
  for (int ct = 0; ct < 4; ++ct) {
    int col = wave * 64 + ct * 16 + l16;
#pragma unroll
    for (int rt = 0; rt < NRT; ++rt)
#pragma unroll
      for (int r = 0; r < 4; ++r) {
        int row = rt * 16 + quad * 4 + r;
        P[(size_t)(row0 + row) * NF + col] = (_Float16)acc[rt][ct][r];
      }
  }
  __syncthreads();                       // all E reads done — LDS reusable

  // ---- fused pstep-1 aggregation epilogue (exact fp32 acc)
  {
    float* Rs = (float*)S;               // 32 x 256 fp32 R-tile (32KB)
    int bi    = row0 >> 6;
    int jbase = row0 & 63;               // 0 or 32
    int b     = row0 >> 12;
    for (int idx = tid; idx < ROWS * NF; idx += 256) {
      int rr = idx >> 8, cc = idx & 255;
      Rs[idx] = R[(size_t)(b * NN + jbase + rr) * NF + cc];
    }
    __syncthreads();
#pragma unroll
    for (int ct = 0; ct < 4; ++ct) {
      int col = wave * 64 + ct * 16 + l16;
      float q = Q[bi * NF + col];
      float s = 0.f;
#pragma unroll
      for (int rt = 0; rt < NRT; ++rt)
#pragma unroll
        for (int r = 0; r < 4; ++r) {
          int row = rt * 16 + quad * 4 + r;
          s += fmaxf(acc[rt][ct][r] + q + Rs[row * NF + col], 0.f);
        }
      s += __shfl_xor(s, 16, 64);        // quad butterfly: rows 0..31 summed
      s += __shfl_xor(s, 32, 64);
      if (quad == 0)
        part[((size_t)bi * 2 + (jbase >> 5)) * NF + col] = s;
    }
  }
#undef ZERO_ACC
#undef STAGE
}

// ---------------------------------------------------------------------------
// upd_qr with k-split GEMMs (R13, frozen).
// ---------------------------------------------------------------------------
__global__ __launch_bounds__(1024) void upd_qr_kernel(
    const float* __restrict__ part, const float* __restrict__ obj,
    const float* __restrict__ ppw, const float* __restrict__ ppb,
    const float* __restrict__ rpw, const float* __restrict__ rpb,
    float* __restrict__ obj_out, float* __restrict__ Qo, float* __restrict__ Ro)
{
  __shared__ float A[4 * NF];
  __shared__ float G[4 * NF];
  __shared__ __align__(16) float red[16 * NF];
  int tid = threadIdx.x;
  int row0 = blockIdx.x * 4;
  int r = tid >> 8, c = tid & 255;
  int kseg = tid >> 8, rsel = (tid >> 6) & 3, c4 = (tid & 63) * 4;
  A[r * NF + c] = obj[(row0 + r) * NF + c];
  G[r * NF + c] = part[((size_t)(row0 + r) * 2 + 0) * NF + c]
                + part[((size_t)(row0 + r) * 2 + 1) * NF + c];
  __syncthreads();
  {
    float4 p = gemm4_k64(ppw, A, kseg, rsel, c4);
    float4 q = gemm4_k64(ppw + NF * NF, G, kseg, rsel, c4);
    p.x += q.x; p.y += q.y; p.z += q.z; p.w += q.w;
    *(float4*)(&red[(kseg * 4 + rsel) * NF + c4]) = p;
  }
  __syncthreads();
  {
    float a = ppb[c] + red[(0 + r) * NF + c] + red[(4 + r) * NF + c]
            + red[(8 + r) * NF + c] + red[(12 + r) * NF + c];
    float o = fmaxf(a, 0.f);
    A[r * NF + c] = o;
    obj_out[(row0 + r) * NF + c] = o;
  }
  __syncthreads();
  {
    float4 p = gemm4_k64(rpw + 256 * NF, A, kseg, rsel, c4);
    *(float4*)(&red[(kseg * 4 + rsel) * NF + c4]) = p;
  }
  __syncthreads();
  Qo[(row0 + r) * NF + c] = rpb[c] + red[(0 + r) * NF + c] + red[(4 + r) * NF + c]
                          + red[(8 + r) * NF + c] + red[(12 + r) * NF + c];
  __syncthreads();
  {
    float4 p = gemm4_k64(rpw + 512 * NF, A, kseg, rsel, c4);
    *(float4*)(&red[(kseg * 4 + rsel) * NF + c4]) = p;
  }
  __syncthreads();
  Ro[(row0 + r) * NF + c] = red[(0 + r) * NF + c] + red[(4 + r) * NF + c]
                          + red[(8 + r) * NF + c] + red[(12 + r) * NF + c];
}

// ---------------------------------------------------------------------------
// agg_part: fp16 P streaming sweep. grid (1024,2) x 256; 8B/lane P loads
// (half4), fp32 accumulation.
// ---------------------------------------------------------------------------
__global__ __launch_bounds__(256) void agg_part_kernel(
    const _Float16* __restrict__ P, const float* __restrict__ Q,
    const float* __restrict__ R, float* __restrict__ part)
{
  __shared__ float red[4 * NF];
  int bi = blockIdx.x;
  int jh = blockIdx.y;
  int tid = threadIdx.x;
  int c4 = (tid & 63) * 4;
  int jq = tid >> 6;
  int b = bi >> 6;
  float4 q4 = *(const float4*)(Q + bi * NF + c4);
  const _Float16* Pb = P + ((size_t)bi * NN + jh * 32 + jq * 8) * NF + c4;
  const float* Rb = R + (size_t)(b * NN + jh * 32 + jq * 8) * NF + c4;
  float4 s = make_float4(0.f, 0.f, 0.f, 0.f);
#pragma unroll
  for (int j = 0; j < 8; ++j) {
    half4 ph  = *(const half4*)(Pb + (size_t)j * NF);
    float4 rv = *(const float4*)(Rb + (size_t)j * NF);
    s.x += fmaxf((float)ph[0] + q4.x + rv.x, 0.f);
    s.y += fmaxf((float)ph[1] + q4.y + rv.y, 0.f);
    s.z += fmaxf((float)ph[2] + q4.z + rv.z, 0.f);
    s.w += fmaxf((float)ph[3] + q4.w + rv.w, 0.f);
  }
  *(float4*)(&red[jq * NF + c4]) = s;
  __syncthreads();
  if (jq == 0) {
    float4 t0 = *(const float4*)(&red[0 * NF + c4]);
    float4 t1 = *(const float4*)(&red[1 * NF + c4]);
    float4 t2 = *(const float4*)(&red[2 * NF + c4]);
    float4 t3 = *(const float4*)(&red[3 * NF + c4]);
    float4 o;
    o.x = t0.x + t1.x + t2.x + t3.x;
    o.y = t0.y + t1.y + t2.y + t3.y;
    o.z = t0.z + t1.z + t2.z + t3.z;
    o.w = t0.w + t1.w + t2.w + t3.w;
    *(float4*)(part + ((size_t)bi * 2 + jh) * NF + c4) = o;
  }
}

// ---------------------------------------------------------------------------
// Final update + predictor with k-split GEMMs (R13, frozen).
// ---------------------------------------------------------------------------
__global__ __launch_bounds__(1024) void upd_pred_kernel(
    const float* __restrict__ part, const float* __restrict__ obj,
    const float* __restrict__ ppw, const float* __restrict__ ppb,
    const float* __restrict__ w0, const float* __restrict__ b0,
    const float* __restrict__ w1, const float* __restrict__ b1,
    float* __restrict__ out)
{
  __shared__ float A[4 * NF];
  __shared__ float G[4 * NF];
  __shared__ __align__(16) float red[16 * NF];
  int tid = threadIdx.x;
  int row0 = blockIdx.x * 4;
  int r = tid >> 8, c = tid & 255;
  int kseg = tid >> 8, rsel = (tid >> 6) & 3, c4 = (tid & 63) * 4;
  A[r * NF + c] = obj[(row0 + r) * NF + c];
  G[r * NF + c] = part[((size_t)(row0 + r) * 2 + 0) * NF + c]
                + part[((size_t)(row0 + r) * 2 + 1) * NF + c];
  __syncthreads();
  {
    float4 p = gemm4_k64(ppw, A, kseg, rsel, c4);
    float4 q = gemm4_k64(ppw + NF * NF, G, kseg, rsel, c4);
    p.x += q.x; p.y += q.y; p.z += q.z; p.w += q.w;
    *(float4*)(&red[(kseg * 4 + rsel) * NF + c4]) = p;
  }
  __syncthreads();
  {
    float a = ppb[c] + red[(0 + r) * NF + c] + red[(4 + r) * NF + c]
            + red[(8 + r) * NF + c] + red[(12 + r) * NF + c];
    A[r * NF + c] = fmaxf(a, 0.f);     // obj2
  }
  __syncthreads();
  {
    float4 p = gemm4_k64(w0, A, kseg, rsel, c4);
    *(float4*)(&red[(kseg * 4 + rsel) * NF + c4]) = p;
  }
  __syncthreads();
  {
    float a = b0[c] + red[(0 + r) * NF + c] + red[(4 + r) * NF + c]
            + red[(8 + r) * NF + c] + red[(12 + r) * NF + c];
    G[r * NF + c] = fmaxf(a, 0.f);     // T
  }
  __syncthreads();
  {
    int ks8 = tid >> 7, rr = (tid >> 5) & 3, g = tid & 31;
    float s = 0.f;
#pragma unroll 8
    for (int k = 0; k < 32; ++k)
      s += G[rr * NF + ks8 * 32 + k] * w1[(ks8 * 32 + k) * GG + g];
    red[tid] = s;
  }
  __syncthreads();
  if (tid < 4 * GG) {
    int rr = tid >> 5, g = tid & 31;
    float a = b1[g];
#pragma unroll
    for (int ks = 0; ks < 8; ++ks) a += red[ks * 128 + tid];
    out[(row0 + rr) * GG + g] = tanhf(a);
  }
}

extern "C" void kernel_launch(void* const* d_in, const int* in_sizes, int n_in,
                              void* d_out, int out_size, void* d_ws, size_t ws_size,
                              hipStream_t stream)
{
  const float* attrs     = (const float*)d_in[0];
  const float* states    = (const float*)d_in[1];
  const float* rel_attrs = (const float*)d_in[2];
  // d_in[3] = pstep (==2, structural)
  const float* enc_w0  = (const float*)d_in[4];
  const float* enc_b0  = (const float*)d_in[5];
  const float* enc_w1  = (const float*)d_in[6];
  const float* enc_b1  = (const float*)d_in[7];
  const float* rel_w0  = (const float*)d_in[8];
  const float* rel_b0  = (const float*)d_in[9];
  const float* rel_w1  = (const float*)d_in[10];
  const float* rel_b1  = (const float*)d_in[11];
  const float* rp_w    = (const float*)d_in[12];
  const float* rp_b    = (const float*)d_in[13];
  const float* pp_w    = (const float*)d_in[14];
  const float* pp_b    = (const float*)d_in[15];
  const float* pred_w0 = (const float*)d_in[16];
  const float* pred_b0 = (const float*)d_in[17];
  const float* pred_w1 = (const float*)d_in[18];
  const float* pred_b1 = (const float*)d_in[19];
  float* out = (float*)d_out;

  char* ws = (char*)d_ws;
  _Float16* P  = (_Float16*)ws;                             // 32 MB (fp16)
  float* obj0  = (float*)(ws + (size_t)NROWS_REL * NF * sizeof(_Float16));
  float* obj1  = obj0 + NROWS_OBJ * NF;
  float* Q0    = obj1 + NROWS_OBJ * NF;
  float* R0    = Q0 + NROWS_OBJ * NF;
  float* Q1    = R0 + NROWS_OBJ * NF;
  float* R1    = Q1 + NROWS_OBJ * NF;
  float* part1 = R1 + NROWS_OBJ * NF;                       // 2 MB
  float* part2 = part1 + 2 * (size_t)NROWS_OBJ * NF;        // 2 MB
  _Float16* F0 = (_Float16*)(part2 + 2 * (size_t)NROWS_OBJ * NF);
  _Float16* F1 = F0 + F0_ELEMS;
  _Float16* F2 = F1 + F1_ELEMS;

  enc_qr_prep_kernel<<<NROWS_OBJ / 4, 1024, 0, stream>>>(
      attrs, states, enc_w0, enc_b0, enc_w1, enc_b1, rp_w, rp_b,
      rel_w0, rel_w1, F0, F1, F2, obj0, Q0, R0);
  // rel chain ONCE: fused pstep-1 agg + fp16 P store for pstep 2
  rel_agg_store_mfma<<<NROWS_REL / ROWS, 256, 0, stream>>>(
      attrs, states, rel_attrs,
      F0, rel_b0, F1, rel_b1, F2,
      Q0, R0, P, part1);
  upd_qr_kernel<<<NROWS_OBJ / 4, 1024, 0, stream>>>(part1, obj0, pp_w, pp_b,
                                                    rp_w, rp_b, obj1, Q1, R1);
  // pstep 2: fp16 P streaming sweep + final update/predictor
  agg_part_kernel<<<dim3(NROWS_OBJ, 2), 256, 0, stream>>>(P, Q1, R1, part2);
  upd_pred_kernel<<<NROWS_OBJ / 4, 1024, 0, stream>>>(part2, obj1, pp_w, pp_b,
                                                      pred_w0, pred_b0,
                                                      pred_w1, pred_b1, out);
}

// Round 16
// 232.382 us; speedup vs baseline: 1.1960x; 1.0143x over previous
//
#include <hip/hip_runtime.h>
#include <hip/hip_bf16.h>
#include <math.h>

// Problem constants (fixed by reference setup_inputs)
#define BB 16
#define NN 64
#define ATTR 4
#define STATE 16
#define RELD 9
#define GG 32
#define NF 256
#define NROWS_OBJ (BB*NN)        // 1024
#define NROWS_REL (BB*NN*NN)     // 65536

typedef _Float16 half8 __attribute__((ext_vector_type(8)));
typedef _Float16 half4 __attribute__((ext_vector_type(4)));
typedef float  floatx4 __attribute__((ext_vector_type(4)));
typedef unsigned short ushort_t;

// fp16 split: x ~= h + l, |x-(h+l)| ~ 2^-22 |x| (A-operand use only)
__device__ __forceinline__ void split2h(float x, _Float16& h, _Float16& l) {
  h = (_Float16)x;
  l = (_Float16)(x - (float)h);
}

#define F0_ELEMS (2 * 16 * 64 * 8)   // 16384
#define F1_ELEMS (8 * 16 * 64 * 8)   // 65536
#define F_TOTAL  (F0_ELEMS + 2 * F1_ELEMS)

// ---------------------------------------------------------------------------
// k-split GEMM partial (R13, frozen): thread (kseg, rsel, c4) accumulates 4
// cols over 64 k's; float4 weight loads, 8 latency batches.
// ---------------------------------------------------------------------------
__device__ __forceinline__ float4 gemm4_k64(const float* __restrict__ W,
                                            const float* A,
                                            int kseg, int rsel, int c4)
{
  float4 p = make_float4(0.f, 0.f, 0.f, 0.f);
  int k0 = kseg * 64;
#pragma unroll 8
  for (int k = 0; k < 64; ++k) {
    float4 w = *(const float4*)(W + (size_t)(k0 + k) * NF + c4);
    float a = A[rsel * NF + k0 + k];
    p.x += a * w.x; p.y += a * w.y; p.z += a * w.z; p.w += a * w.w;
  }
  return p;
}

// ---------------------------------------------------------------------------
// Fused encoder + Q/R + weight-fragment prep. R15: Q and R GEMMs run in ONE
// phase (gs = tid>>9 picks Q or R; ks2 = (tid>>8)&1 splits K 2-way) —
// halves the serial cold-latency phases.
// ---------------------------------------------------------------------------
__global__ __launch_bounds__(1024) void enc_qr_prep_kernel(
    const float* __restrict__ attrs, const float* __restrict__ states,
    const float* __restrict__ w0, const float* __restrict__ b0,
    const float* __restrict__ w1, const float* __restrict__ b1,
    const float* __restrict__ rpw, const float* __restrict__ rpb,
    const float* __restrict__ rel_w0, const float* __restrict__ rel_w1,
    _Float16* __restrict__ F0, _Float16* __restrict__ F1,
    _Float16* __restrict__ F2,
    float* __restrict__ obj, float* __restrict__ Q, float* __restrict__ R)
{
  int tid = threadIdx.x;
  for (int idx = blockIdx.x * 1024 + tid; idx < F_TOTAL; idx += 256 * 1024) {
    if (idx < F0_ELEMS) {
      int j = idx & 7, lane = (idx >> 3) & 63, g = (idx >> 9) & 15, s = idx >> 13;
      int k = s * 32 + (lane >> 4) * 8 + j, n = g * 16 + (lane & 15);
      float v = (k < 33) ? rel_w0[k * NF + n] : 0.f;
      F0[idx] = (_Float16)v;
    } else if (idx < F0_ELEMS + F1_ELEMS) {
      int t = idx - F0_ELEMS;
      int j = t & 7, lane = (t >> 3) & 63, g = (t >> 9) & 15, s = t >> 13;
      int k = s * 32 + (lane >> 4) * 8 + j, n = g * 16 + (lane & 15);
      F1[t] = (_Float16)rel_w1[k * NF + n];
    } else {
      int t = idx - (F0_ELEMS + F1_ELEMS);
      int j = t & 7, lane = (t >> 3) & 63, g = (t >> 9) & 15, s = t >> 13;
      int k = s * 32 + (lane >> 4) * 8 + j, n = g * 16 + (lane & 15);
      F2[t] = (_Float16)rpw[k * NF + n];
    }
  }
  __shared__ float X[4 * 20];
  __shared__ float H[4 * NF];
  __shared__ float O[4 * NF];
  __shared__ __align__(16) float red[16 * NF];
  int row0 = blockIdx.x * 4;
  if (tid < 80) {
    int r = tid / 20, k = tid % 20;
    int m = row0 + r;
    X[tid] = (k < ATTR) ? attrs[m * ATTR + k] : states[m * STATE + (k - ATTR)];
  }
  __syncthreads();
  int r = tid >> 8, c = tid & 255;
  int kseg = tid >> 8, rsel = (tid >> 6) & 3, c4 = (tid & 63) * 4;
  {
    float a = b0[c];
#pragma unroll
    for (int k = 0; k < 20; ++k) a += X[r * 20 + k] * w0[k * NF + c];
    H[r * NF + c] = fmaxf(a, 0.f);
  }
  __syncthreads();
  {
    float4 p = gemm4_k64(w1, H, kseg, rsel, c4);
    *(float4*)(&red[(kseg * 4 + rsel) * NF + c4]) = p;
  }
  __syncthreads();
  {
    float a = b1[c] + red[(0 + r) * NF + c] + red[(4 + r) * NF + c]
            + red[(8 + r) * NF + c] + red[(12 + r) * NF + c];
    a = fmaxf(a, 0.f);
    O[r * NF + c] = a;
    obj[(row0 + r) * NF + c] = a;
  }
  __syncthreads();
  // Q and R in one phase
  {
    int gs = tid >> 9, ks2 = (tid >> 8) & 1;
    const float* W = gs ? (rpw + 512 * NF) : (rpw + 256 * NF);
    float4 p = gemm4_k64(W, O, ks2 * 2, rsel, c4);
    float4 q = gemm4_k64(W, O, ks2 * 2 + 1, rsel, c4);
    p.x += q.x; p.y += q.y; p.z += q.z; p.w += q.w;
    *(float4*)(&red[((gs * 2 + ks2) * 4 + rsel) * NF + c4]) = p;
  }
  __syncthreads();
  Q[(row0 + r) * NF + c] = rpb[c] + red[(0 + r) * NF + c] + red[(4 + r) * NF + c];
  R[(row0 + r) * NF + c] = red[(8 + r) * NF + c] + red[(12 + r) * NF + c];
}

// ---------------------------------------------------------------------------
// Relation chain, fp16 A-split x B-single MFMA (FROZEN from R14): run ONCE,
// stage-3 P-tile in regs -> fp16 P store + fused pstep-1 agg epilogue.
// ---------------------------------------------------------------------------
#define ROWS 32
#define NRT 2
#define HSTR 264
#define XSTR 72

__global__ __launch_bounds__(256, 4) void rel_agg_store_mfma(
    const float* __restrict__ attrs, const float* __restrict__ states,
    const float* __restrict__ rel_attrs,
    const _Float16* __restrict__ F0, const float* __restrict__ b0,
    const _Float16* __restrict__ F1, const float* __restrict__ b1,
    const _Float16* __restrict__ F2,
    const float* __restrict__ Q, const float* __restrict__ R,
    _Float16* __restrict__ P, float* __restrict__ part)
{
  __shared__ __align__(16) _Float16 S[2 * ROWS * HSTR];   // 33792 B
  _Float16* Hh = S;
  _Float16* Hl = S + ROWS * HSTR;
  _Float16* Xh = Hh;   // X aliased onto H (dead after stage 1)
  _Float16* Xl = Hl;

  int tid  = threadIdx.x;
  int wave = tid >> 6;
  int lane = tid & 63;
  int quad = lane >> 4;
  int l16  = lane & 15;
  int row0 = blockIdx.x * ROWS;

  for (int idx = tid; idx < ROWS * 64; idx += 256) {
    int r = idx >> 6, k = idx & 63;
    int grow = row0 + r;
    int j = grow & 63, i = (grow >> 6) & 63, b = grow >> 12;
    float v = 0.f;
    if (k < RELD)                     v = rel_attrs[(size_t)grow * RELD + k];
    else if (k < RELD + STATE)        v = states[(b * NN + i) * STATE + (k - RELD)]
                                        - states[(b * NN + j) * STATE + (k - RELD)];
    else if (k < RELD + STATE + ATTR) v = attrs[(b * NN + i) * ATTR + (k - RELD - STATE)];
    else if (k < 33)                  v = attrs[(b * NN + j) * ATTR + (k - RELD - STATE - ATTR)];
    _Float16 h, l; split2h(v, h, l);
    Xh[r * XSTR + k] = h;
    Xl[r * XSTR + k] = l;
  }
  __syncthreads();

  floatx4 acc[NRT][4];

#define ZERO_ACC() do { \
  _Pragma("unroll") for (int rt = 0; rt < NRT; ++rt) \
  _Pragma("unroll") for (int ct = 0; ct < 4; ++ct) acc[rt][ct] = (floatx4)(0.f); } while (0)

#define STAGE(Sn, AH, AL, ASTR, BF) do { \
  half8 ah[2][NRT], al[2][NRT], bf[2][4]; \
  _Pragma("unroll") for (int ct = 0; ct < 4; ++ct) \
    bf[0][ct] = *(const half8*)((BF) + (size_t)((wave * 4 + ct) * 64 + lane) * 8); \
  _Pragma("unroll") for (int rt = 0; rt < NRT; ++rt) { \
    ah[0][rt] = *(const half8*)(&(AH)[(rt * 16 + l16) * (ASTR) + quad * 8]); \
    al[0][rt] = *(const half8*)(&(AL)[(rt * 16 + l16) * (ASTR) + quad * 8]); } \
  _Pragma("unroll") \
  for (int s = 0; s < (Sn); ++s) { \
    int cur = s & 1, nxt = cur ^ 1; \
    if (s + 1 < (Sn)) { \
      _Pragma("unroll") for (int ct = 0; ct < 4; ++ct) \
        bf[nxt][ct] = *(const half8*)((BF) + (size_t)(((s + 1) * 16 + wave * 4 + ct) * 64 + lane) * 8); \
      _Pragma("unroll") for (int rt = 0; rt < NRT; ++rt) { \
        ah[nxt][rt] = *(const half8*)(&(AH)[(rt * 16 + l16) * (ASTR) + (s + 1) * 32 + quad * 8]); \
        al[nxt][rt] = *(const half8*)(&(AL)[(rt * 16 + l16) * (ASTR) + (s + 1) * 32 + quad * 8]); } } \
    _Pragma("unroll") for (int rt = 0; rt < NRT; ++rt) \
    _Pragma("unroll") for (int ct = 0; ct < 4; ++ct) { \
      acc[rt][ct] = __builtin_amdgcn_mfma_f32_16x16x32_f16(ah[cur][rt], bf[cur][ct], acc[rt][ct], 0, 0, 0); \
      acc[rt][ct] = __builtin_amdgcn_mfma_f32_16x16x32_f16(al[cur][rt], bf[cur][ct], acc[rt][ct], 0, 0, 0); } \
  } } while (0)

  // ---- stage 1: H = ReLU(X @ W0 + b0), K=64 (padded)
  ZERO_ACC();
  STAGE(2, Xh, Xl, XSTR, F0);
  __syncthreads();  // X reads done before H overwrites the aliased region
#pragma unroll
  for (int ct = 0; ct < 4; ++ct) {
    int col = wave * 64 + ct * 16 + l16;
    float bias = b0[col];
#pragma unroll
    for (int rt = 0; rt < NRT; ++rt)
#pragma unroll
      for (int r = 0; r < 4; ++r) {
        int row = rt * 16 + quad * 4 + r;
        float h = fmaxf(acc[rt][ct][r] + bias, 0.f);
        split2h(h, Hh[row * HSTR + col], Hl[row * HSTR + col]);
      }
  }
  __syncthreads();

  // ---- stage 2: E = ReLU(H @ W1 + b1), K=256
  ZERO_ACC();
  STAGE(8, Hh, Hl, HSTR, F1);
  __syncthreads();
#pragma unroll
  for (int ct = 0; ct < 4; ++ct) {
    int col = wave * 64 + ct * 16 + l16;
    float bias = b1[col];
#pragma unroll
    for (int rt = 0; rt < NRT; ++rt)
#pragma unroll
      for (int r = 0; r < 4; ++r) {
        int row = rt * 16 + quad * 4 + r;
        float e = fmaxf(acc[rt][ct][r] + bias, 0.f);
        split2h(e, Hh[row * HSTR + col], Hl[row * HSTR + col]);
      }
  }
  __syncthreads();

  // ---- stage 3: P-tile in registers (K=256)
  ZERO_ACC();
  STAGE(8, Hh, Hl, HSTR, F2);

  // ---- store P fp16 (pstep 2 reads it in aggupd_pred)
#pragma unroll
  for (int ct = 0; ct < 4; ++ct) {
    int col = wave * 64 + ct * 16 + l16;
#pragma unroll
    for (int rt = 0; rt < NRT; ++rt)
#pragma unroll
      for (int r = 0; r < 4; ++r) {
        int row = rt * 16 + quad * 4 + r;
        P[(size_t)(row0 + row) * NF + col] = (_Float16)acc[rt][ct][r];
      }
  }
  __syncthreads();                       // all E reads done — LDS reusable

  // ---- fused pstep-1 aggregation epilogue (exact fp32 acc)
  {
    float* Rs = (float*)S;               // 32 x 256 fp32 R-tile (32KB)
    int bi    = row0 >> 6;
    int jbase = row0 & 63;               // 0 or 32
    int b     = row0 >> 12;
    for (int idx = tid; idx < ROWS * NF; idx += 256) {
      int rr = idx >> 8, cc = idx & 255;
      Rs[idx] = R[(size_t)(b * NN + jbase + rr) * NF + cc];
    }
    __syncthreads();
#pragma unroll
    for (int ct = 0; ct < 4; ++ct) {
      int col = wave * 64 + ct * 16 + l16;
      float q = Q[bi * NF + col];
      float s = 0.f;
#pragma unroll
      for (int rt = 0; rt < NRT; ++rt)
#pragma unroll
        for (int r = 0; r < 4; ++r) {
          int row = rt * 16 + quad * 4 + r;
          s += fmaxf(acc[rt][ct][r] + q + Rs[row * NF + col], 0.f);
        }
      s += __shfl_xor(s, 16, 64);        // quad butterfly: rows 0..31 summed
      s += __shfl_xor(s, 32, 64);
      if (quad == 0)
        part[((size_t)bi * 2 + (jbase >> 5)) * NF + col] = s;
    }
  }
#undef ZERO_ACC
#undef STAGE
}

// ---------------------------------------------------------------------------
// upd_qr: R15 — Q and R GEMMs in one phase (gs/ks2 split).
// ---------------------------------------------------------------------------
__global__ __launch_bounds__(1024) void upd_qr_kernel(
    const float* __restrict__ part, const float* __restrict__ obj,
    const float* __restrict__ ppw, const float* __restrict__ ppb,
    const float* __restrict__ rpw, const float* __restrict__ rpb,
    float* __restrict__ obj_out, float* __restrict__ Qo, float* __restrict__ Ro)
{
  __shared__ float A[4 * NF];
  __shared__ float G[4 * NF];
  __shared__ __align__(16) float red[16 * NF];
  int tid = threadIdx.x;
  int row0 = blockIdx.x * 4;
  int r = tid >> 8, c = tid & 255;
  int kseg = tid >> 8, rsel = (tid >> 6) & 3, c4 = (tid & 63) * 4;
  A[r * NF + c] = obj[(row0 + r) * NF + c];
  G[r * NF + c] = part[((size_t)(row0 + r) * 2 + 0) * NF + c]
                + part[((size_t)(row0 + r) * 2 + 1) * NF + c];
  __syncthreads();
  {
    float4 p = gemm4_k64(ppw, A, kseg, rsel, c4);
    float4 q = gemm4_k64(ppw + NF * NF, G, kseg, rsel, c4);
    p.x += q.x; p.y += q.y; p.z += q.z; p.w += q.w;
    *(float4*)(&red[(kseg * 4 + rsel) * NF + c4]) = p;
  }
  __syncthreads();
  {
    float a = ppb[c] + red[(0 + r) * NF + c] + red[(4 + r) * NF + c]
            + red[(8 + r) * NF + c] + red[(12 + r) * NF + c];
    float o = fmaxf(a, 0.f);
    A[r * NF + c] = o;
    obj_out[(row0 + r) * NF + c] = o;
  }
  __syncthreads();
  // Q' and R' in one phase
  {
    int gs = tid >> 9, ks2 = (tid >> 8) & 1;
    const float* W = gs ? (rpw + 512 * NF) : (rpw + 256 * NF);
    float4 p = gemm4_k64(W, A, ks2 * 2, rsel, c4);
    float4 q = gemm4_k64(W, A, ks2 * 2 + 1, rsel, c4);
    p.x += q.x; p.y += q.y; p.z += q.z; p.w += q.w;
    *(float4*)(&red[((gs * 2 + ks2) * 4 + rsel) * NF + c4]) = p;
  }
  __syncthreads();
  Qo[(row0 + r) * NF + c] = rpb[c] + red[(0 + r) * NF + c] + red[(4 + r) * NF + c];
  Ro[(row0 + r) * NF + c] = red[(8 + r) * NF + c] + red[(12 + r) * NF + c];
}

// ---------------------------------------------------------------------------
// R15: fused pstep-2 agg + final update + predictor (one dispatch; part2
// eliminated). Grid 256 x 1024. Sweep: thread (c4=(tid&63)*4, rr=(tid>>6)&3,
// jq=tid>>8) streams 16 j of fp16 P (half4) + R; 4-way LDS reduce -> G.
// Then R13's k-split update/pred phases.
// ---------------------------------------------------------------------------
__global__ __launch_bounds__(1024) void aggupd_pred_kernel(
    const _Float16* __restrict__ P, const float* __restrict__ Q,
    const float* __restrict__ R, const float* __restrict__ obj,
    const float* __restrict__ ppw, const float* __restrict__ ppb,
    const float* __restrict__ w0, const float* __restrict__ b0,
    const float* __restrict__ w1, const float* __restrict__ b1,
    float* __restrict__ out)
{
  __shared__ float A[4 * NF];
  __shared__ float G[4 * NF];
  __shared__ __align__(16) float red[16 * NF];
  int tid = threadIdx.x;
  int row0 = blockIdx.x * 4;
  int b = row0 >> 6;
  int r = tid >> 8, c = tid & 255;
  int kseg = tid >> 8, rsel = (tid >> 6) & 3, c4 = (tid & 63) * 4;
  // ---- pstep-2 agg sweep
  {
    int rr = (tid >> 6) & 3;
    int jq = tid >> 8;
    float4 q4 = *(const float4*)(Q + (row0 + rr) * NF + c4);
    const _Float16* Pb = P + ((size_t)(row0 + rr) * NN + jq * 16) * NF + c4;
    const float* Rb = R + (size_t)(b * NN + jq * 16) * NF + c4;
    float4 s = make_float4(0.f, 0.f, 0.f, 0.f);
#pragma unroll
    for (int j = 0; j < 16; ++j) {
      half4 ph  = *(const half4*)(Pb + (size_t)j * NF);
      float4 rv = *(const float4*)(Rb + (size_t)j * NF);
      s.x += fmaxf((float)ph[0] + q4.x + rv.x, 0.f);
      s.y += fmaxf((float)ph[1] + q4.y + rv.y, 0.f);
      s.z += fmaxf((float)ph[2] + q4.z + rv.z, 0.f);
      s.w += fmaxf((float)ph[3] + q4.w + rv.w, 0.f);
    }
    *(float4*)(&red[(jq * 4 + rr) * NF + c4]) = s;
    A[r * NF + c] = obj[(row0 + r) * NF + c];
  }
  __syncthreads();
  G[r * NF + c] = red[(0 + r) * NF + c] + red[(4 + r) * NF + c]
                + red[(8 + r) * NF + c] + red[(12 + r) * NF + c];
  __syncthreads();
  // ---- update GEMM
  {
    float4 p = gemm4_k64(ppw, A, kseg, rsel, c4);
    float4 q = gemm4_k64(ppw + NF * NF, G, kseg, rsel, c4);
    p.x += q.x; p.y += q.y; p.z += q.z; p.w += q.w;
    *(float4*)(&red[(kseg * 4 + rsel) * NF + c4]) = p;
  }
  __syncthreads();
  {
    float a = ppb[c] + red[(0 + r) * NF + c] + red[(4 + r) * NF + c]
            + red[(8 + r) * NF + c] + red[(12 + r) * NF + c];
    A[r * NF + c] = fmaxf(a, 0.f);     // obj2
  }
  __syncthreads();
  // ---- predictor stage 1
  {
    float4 p = gemm4_k64(w0, A, kseg, rsel, c4);
    *(float4*)(&red[(kseg * 4 + rsel) * NF + c4]) = p;
  }
  __syncthreads();
  {
    float a = b0[c] + red[(0 + r) * NF + c] + red[(4 + r) * NF + c]
            + red[(8 + r) * NF + c] + red[(12 + r) * NF + c];
    G[r * NF + c] = fmaxf(a, 0.f);     // T
  }
  __syncthreads();
  // ---- predictor stage 2: out = tanh(T @ w1 + b1), 8-way k-split
  {
    int ks8 = tid >> 7, rr = (tid >> 5) & 3, g = tid & 31;
    float s = 0.f;
#pragma unroll 8
    for (int k = 0; k < 32; ++k)
      s += G[rr * NF + ks8 * 32 + k] * w1[(ks8 * 32 + k) * GG + g];
    red[tid] = s;
  }
  __syncthreads();
  if (tid < 4 * GG) {
    int rr = tid >> 5, g = tid & 31;
    float a = b1[g];
#pragma unroll
    for (int ks = 0; ks < 8; ++ks) a += red[ks * 128 + tid];
    out[(row0 + rr) * GG + g] = tanhf(a);
  }
}

extern "C" void kernel_launch(void* const* d_in, const int* in_sizes, int n_in,
                              void* d_out, int out_size, void* d_ws, size_t ws_size,
                              hipStream_t stream)
{
  const float* attrs     = (const float*)d_in[0];
  const float* states    = (const float*)d_in[1];
  const float* rel_attrs = (const float*)d_in[2];
  // d_in[3] = pstep (==2, structural)
  const float* enc_w0  = (const float*)d_in[4];
  const float* enc_b0  = (const float*)d_in[5];
  const float* enc_w1  = (const float*)d_in[6];
  const float* enc_b1  = (const float*)d_in[7];
  const float* rel_w0  = (const float*)d_in[8];
  const float* rel_b0  = (const float*)d_in[9];
  const float* rel_w1  = (const float*)d_in[10];
  const float* rel_b1  = (const float*)d_in[11];
  const float* rp_w    = (const float*)d_in[12];
  const float* rp_b    = (const float*)d_in[13];
  const float* pp_w    = (const float*)d_in[14];
  const float* pp_b    = (const float*)d_in[15];
  const float* pred_w0 = (const float*)d_in[16];
  const float* pred_b0 = (const float*)d_in[17];
  const float* pred_w1 = (const float*)d_in[18];
  const float* pred_b1 = (const float*)d_in[19];
  float* out = (float*)d_out;

  char* ws = (char*)d_ws;
  _Float16* P  = (_Float16*)ws;                             // 32 MB (fp16)
  float* obj0  = (float*)(ws + (size_t)NROWS_REL * NF * sizeof(_Float16));
  float* obj1  = obj0 + NROWS_OBJ * NF;
  float* Q0    = obj1 + NROWS_OBJ * NF;
  float* R0    = Q0 + NROWS_OBJ * NF;
  float* Q1    = R0 + NROWS_OBJ * NF;
  float* R1    = Q1 + NROWS_OBJ * NF;
  float* part1 = R1 + NROWS_OBJ * NF;                       // 2 MB
  _Float16* F0 = (_Float16*)(part1 + 2 * (size_t)NROWS_OBJ * NF);
  _Float16* F1 = F0 + F0_ELEMS;
  _Float16* F2 = F1 + F1_ELEMS;

  enc_qr_prep_kernel<<<NROWS_OBJ / 4, 1024, 0, stream>>>(
      attrs, states, enc_w0, enc_b0, enc_w1, enc_b1, rp_w, rp_b,
      rel_w0, rel_w1, F0, F1, F2, obj0, Q0, R0);
  // rel chain ONCE: fused pstep-1 agg + fp16 P store for pstep 2
  rel_agg_store_mfma<<<NROWS_REL / ROWS, 256, 0, stream>>>(
      attrs, states, rel_attrs,
      F0, rel_b0, F1, rel_b1, F2,
      Q0, R0, P, part1);
  upd_qr_kernel<<<NROWS_OBJ / 4, 1024, 0, stream>>>(part1, obj0, pp_w, pp_b,
                                                    rp_w, rp_b, obj1, Q1, R1);
  // pstep 2: fused agg + update + predictor (part2 eliminated)
  aggupd_pred_kernel<<<NROWS_OBJ / 4, 1024, 0, stream>>>(P, Q1, R1, obj1,
                                                         pp_w, pp_b,
                                                         pred_w0, pred_b0,
                                                         pred_w1, pred_b1, out);
}